// Round 1
// 2069.132 us; speedup vs baseline: 2.3059x; 2.3059x over previous
//
#include <hip/hip_runtime.h>

#define DEVINL __device__ __forceinline__

// ---- ordered-uint encoding for float atomicMax (bit-exact max semantics) ----
DEVINL unsigned fenc(float f) {
    unsigned u = __float_as_uint(f);
    return (u & 0x80000000u) ? ~u : (u | 0x80000000u);
}
DEVINL float fdec(unsigned k) {
    unsigned u = (k & 0x80000000u) ? (k ^ 0x80000000u) : ~k;
    return __uint_as_float(u);
}

// ---- async global->LDS copy, 4 bytes per lane ----
DEVINL void gload_lds4(const float* g, float* l) {
    __builtin_amdgcn_global_load_lds(
        (const __attribute__((address_space(1))) unsigned int*)(const void*)g,
        (__attribute__((address_space(3))) unsigned int*)(void*)l,
        4, 0, 0);
}

// ---- zero init (ws is poisoned 0xAA before every call) ----
__global__ void zero_kernel(float* __restrict__ p, long n) {
    long i = (long)blockIdx.x * blockDim.x + threadIdx.x;
    long stride = (long)gridDim.x * blockDim.x;
    for (; i < n; i += stride) p[i] = 0.f;
}

// ---- node transform: xl = x@Wl + bl, xr = x@Wr + br (optionally gathered x) ----
template<int IN, int HC>
__global__ __launch_bounds__(256) void node_transform(
    const float* __restrict__ x, const int* __restrict__ gather,
    const float* __restrict__ Wl, const float* __restrict__ bl,
    const float* __restrict__ Wr, const float* __restrict__ br,
    float* __restrict__ xl, float* __restrict__ xr, int N)
{
    __shared__ float Wls[IN * HC];
    __shared__ float Wrs[IN * HC];
    for (int i = threadIdx.x; i < IN * HC; i += 256) { Wls[i] = Wl[i]; Wrs[i] = Wr[i]; }
    __syncthreads();
    constexpr int NPB = 256 / HC;
    const int c = threadIdx.x % HC;
    const int n = blockIdx.x * NPB + threadIdx.x / HC;
    if (n >= N) return;
    const int row = gather ? gather[n] : n;
    const float* xp = x + (long)row * IN;
    float al = bl[c], ar = br[c];
#pragma unroll
    for (int k = 0; k < IN; ++k) {
        float v = xp[k];
        al = fmaf(v, Wls[k * HC + c], al);
        ar = fmaf(v, Wrs[k * HC + c], ar);
    }
    xl[(long)n * HC + c] = al;
    xr[(long)n * HC + c] = ar;
}

// ---- fused edge pass: ea = eattr@We (async-staged tiled SGEMM), then
//      logit[e,h] = sum_c att[h,c]*leaky(ea + xl[src] + xr[dst]); atomicMax per dst ----
// Staging uses global_load_lds with a source-side XOR swizzle (16B granularity):
//   LDS dest is linear (HW requirement); logical col k of row r is stored at
//   c' = k ^ (((r>>2)&7)<<2).  Reads apply the same XOR -> conflict-free b128.
template<int HC, int OPT, int EPT>
__global__ __launch_bounds__(256) void gat_edge(
    const float* __restrict__ eattr,
    const float* __restrict__ xl, const float* __restrict__ xr,
    const float* __restrict__ We, const float* __restrict__ att,
    const int* __restrict__ src, const int* __restrict__ dst,
    float* __restrict__ logits, unsigned* __restrict__ mkey, int E)
{
    constexpr int H = HC / 16;
    constexpr int TX = HC / OPT;      // threads along out dim
    constexpr int TY = 256 / TX;      // threads along edge dim
    constexpr int TILE_E = TY * EPT;
    constexpr int KC = 32;
    constexpr int NKM = 12;           // 12*32 = 384 main cols; col 384 peeled to tail
    static_assert(TILE_E == 128, "tile geometry");
    static_assert((KC * HC) % 256 == 0, "B staging");
    static_assert((TILE_E * KC) / 256 == 16, "A staging");

    __shared__ float As[TILE_E * KC];   // swizzled storage, linear for global_load_lds
    __shared__ float Bs[KC * HC];       // [kk][n], linear
    __shared__ float Blast[HC];         // We row 384
    __shared__ float part[TILE_E][TX + 1];

    const int tid = threadIdx.x;
    const int tx = tid % TX, ty = tid / TX;
    const long eblk = (long)blockIdx.x * TILE_E;

    if (tid < HC) Blast[tid] = We[384 * HC + tid];

    float acc[EPT][OPT];
#pragma unroll
    for (int i = 0; i < EPT; ++i)
#pragma unroll
        for (int j = 0; j < OPT; ++j) acc[i][j] = 0.f;

    for (int kc = 0; kc < NKM; ++kc) {
        const int k0 = kc * KC;
        // ---- A tile: 128x32 floats, 16 async dwords/thread, source pre-swizzled ----
#pragma unroll
        for (int i = 0; i < 16; ++i) {
            const int idx = tid + i * 256;
            const int row = idx >> 5;          // 0..127
            const int c   = idx & 31;
            const int klog = (((c >> 2) ^ ((row >> 2) & 7)) << 2) | (c & 3);
            long ge = eblk + row;
            ge = (ge < E) ? ge : (long)(E - 1);   // clamp; results discarded in epilogue
            gload_lds4(eattr + ge * 385 + (k0 + klog), &As[idx]);
        }
        // ---- B tile: KCxHC floats, linear source (We[k0*HC ..]) ----
        constexpr int BELEM = KC * HC / 256;
#pragma unroll
        for (int i = 0; i < BELEM; ++i) {
            const int idx = tid + i * 256;
            gload_lds4(We + (long)k0 * HC + idx, &Bs[idx]);
        }
        asm volatile("s_waitcnt vmcnt(0)" ::: "memory");
        __syncthreads();

        // ---- compute: 8 groups of 4 k-steps; A via conflict-free b128 ----
#pragma unroll
        for (int g = 0; g < 8; ++g) {
            float a[EPT][4];
#pragma unroll
            for (int i = 0; i < EPT; ++i) {
                const int row = ty * EPT + i;
                const float4 v = *(const float4*)&As[row * KC + ((g ^ ((row >> 2) & 7)) << 2)];
                a[i][0] = v.x; a[i][1] = v.y; a[i][2] = v.z; a[i][3] = v.w;
            }
#pragma unroll
            for (int q = 0; q < 4; ++q) {
                float b[OPT];
#pragma unroll
                for (int j = 0; j < OPT; j += 4) {
                    const float4 bv = *(const float4*)&Bs[(g * 4 + q) * HC + tx * OPT + j];
                    b[j] = bv.x; b[j + 1] = bv.y; b[j + 2] = bv.z; b[j + 3] = bv.w;
                }
#pragma unroll
                for (int i = 0; i < EPT; ++i)
#pragma unroll
                    for (int j = 0; j < OPT; ++j)
                        acc[i][j] = fmaf(a[i][q], b[j], acc[i][j]);
            }
        }
        __syncthreads();
    }

    // ---- epilogue: fold k=384 term, add gathered xl/xr, leaky, dot with att ----
    const int h = (tx * OPT) / 16;
    const int cb = (tx * OPT) % 16;
    float av[OPT], bl[OPT];
#pragma unroll
    for (int j = 0; j < OPT; ++j) {
        av[j] = att[h * 16 + cb + j];
        bl[j] = Blast[tx * OPT + j];
    }

#pragma unroll
    for (int i = 0; i < EPT; ++i) {
        const int el = ty * EPT + i;
        const long ge = eblk + el;
        float p = 0.f;
        if (ge < E) {
            const float a384 = eattr[ge * 385 + 384];
            const float* xlp = xl + (long)src[ge] * HC + tx * OPT;
            const float* xrp = xr + (long)dst[ge] * HC + tx * OPT;
#pragma unroll
            for (int j = 0; j < OPT; j += 4) {
                const float4 vj = *(const float4*)(xlp + j);
                const float4 vi = *(const float4*)(xrp + j);
                float t0 = fmaf(a384, bl[j + 0], acc[i][j + 0]) + vj.x + vi.x;
                float t1 = fmaf(a384, bl[j + 1], acc[i][j + 1]) + vj.y + vi.y;
                float t2 = fmaf(a384, bl[j + 2], acc[i][j + 2]) + vj.z + vi.z;
                float t3 = fmaf(a384, bl[j + 3], acc[i][j + 3]) + vj.w + vi.w;
                t0 = (t0 > 0.f) ? t0 : 0.2f * t0;
                t1 = (t1 > 0.f) ? t1 : 0.2f * t1;
                t2 = (t2 > 0.f) ? t2 : 0.2f * t2;
                t3 = (t3 > 0.f) ? t3 : 0.2f * t3;
                p = fmaf(t0, av[j + 0], p);
                p = fmaf(t1, av[j + 1], p);
                p = fmaf(t2, av[j + 2], p);
                p = fmaf(t3, av[j + 3], p);
            }
        }
        part[el][tx] = p;
    }
    __syncthreads();

    constexpr int G = 16 / OPT;   // threads contributing per (edge, head)
    for (int idx = tid; idx < TILE_E * H; idx += 256) {
        const int e = idx / H, hh = idx % H;
        const long ge = eblk + e;
        if (ge < E) {
            float l = 0.f;
#pragma unroll
            for (int g = 0; g < G; ++g) l += part[e][hh * G + g];
            logits[ge * H + hh] = l;
            atomicMax(&mkey[(unsigned)dst[ge] * H + hh], fenc(l));
        }
    }
}

// ---- softmax pass B: ex = exp(logit - max); atomic sum per dst; in-place store ----
template<int H>
__global__ __launch_bounds__(256) void softmax_ex(
    float* __restrict__ lg, const unsigned* __restrict__ mkey,
    float* __restrict__ ssum, const int* __restrict__ dst, int E)
{
    int idx = blockIdx.x * 256 + threadIdx.x;
    if (idx >= E * H) return;
    int e = idx / H, h = idx % H;
    int d = dst[e];
    float m = fdec(mkey[d * H + h]);
    float ex = expf(lg[idx] - m);
    lg[idx] = ex;
    atomicAdd(&ssum[d * H + h], ex);
}

// ---- pass C: acc[dst] += xl[src] * alpha ----
template<int HC>
__global__ __launch_bounds__(256) void aggregate(
    const float* __restrict__ ex, const float* __restrict__ ssum,
    const float* __restrict__ xl, const int* __restrict__ src,
    const int* __restrict__ dst, float* __restrict__ acc, int E)
{
    constexpr int H = HC / 16;
    long idx = (long)blockIdx.x * 256 + threadIdx.x;
    if (idx >= (long)E * HC) return;
    int e = (int)(idx / HC), c = (int)(idx % HC);
    int h = c / 16;
    int d = dst[e];
    float alpha = ex[(long)e * H + h] / (ssum[d * H + h] + 1e-16f);
    atomicAdd(&acc[(long)d * HC + c], xl[(long)src[e] * HC + c] * alpha);
}

// ---- finalize: x = (acc + bias), optional ELU ----
__global__ __launch_bounds__(256) void finalize_k(
    const float* __restrict__ acc, const float* __restrict__ bias,
    float* __restrict__ xout, int total, int HC, int do_elu)
{
    int idx = blockIdx.x * 256 + threadIdx.x;
    if (idx >= total) return;
    float v = acc[idx] + bias[idx % HC];
    if (do_elu) v = (v > 0.f) ? v : expm1f(v);
    xout[idx] = v;
}

// ---- edge MLP: out[e] = W3 @ relu(W2 @ relu(W1 @ [x3[src], x3[dst]] + b1) + b2) + b3 ----
__global__ __launch_bounds__(256) void edge_mlp(
    const float* __restrict__ x3, const int* __restrict__ src, const int* __restrict__ dst,
    const float* __restrict__ W1, const float* __restrict__ b1,
    const float* __restrict__ W2, const float* __restrict__ b2,
    const float* __restrict__ W3, const float* __restrict__ b3,
    float* __restrict__ out, int E)
{
    int e = blockIdx.x * 256 + threadIdx.x;
    if (e >= E) return;
    float in[32];
    const float* xs = x3 + (long)src[e] * 16;
    const float* xd = x3 + (long)dst[e] * 16;
#pragma unroll
    for (int k = 0; k < 16; k += 4) {
        float4 a = *(const float4*)(xs + k);
        float4 b = *(const float4*)(xd + k);
        in[k] = a.x; in[k + 1] = a.y; in[k + 2] = a.z; in[k + 3] = a.w;
        in[16 + k] = b.x; in[16 + k + 1] = b.y; in[16 + k + 2] = b.z; in[16 + k + 3] = b.w;
    }
    // layer 1: 32 -> 64 (W uniform-indexed -> scalar loads)
    float h1[64];
#pragma unroll
    for (int j = 0; j < 64; ++j) h1[j] = b1[j];
#pragma unroll
    for (int k = 0; k < 32; ++k) {
        float a = in[k];
#pragma unroll
        for (int j = 0; j < 64; ++j) h1[j] = fmaf(a, W1[k * 64 + j], h1[j]);
    }
    // layer 2: 64 -> 32 (relu on h1 applied at consumption)
    float h2[32];
#pragma unroll
    for (int j = 0; j < 32; ++j) h2[j] = b2[j];
#pragma unroll
    for (int k = 0; k < 64; ++k) {
        float a = h1[k] > 0.f ? h1[k] : 0.f;
#pragma unroll
        for (int j = 0; j < 32; ++j) h2[j] = fmaf(a, W2[k * 32 + j], h2[j]);
    }
    // layer 3: 32 -> 1
    float o = b3[0];
#pragma unroll
    for (int j = 0; j < 32; ++j) {
        float a = h2[j] > 0.f ? h2[j] : 0.f;
        o = fmaf(a, W3[j], o);
    }
    out[e] = o;
}

extern "C" void kernel_launch(void* const* d_in, const int* in_sizes, int n_in,
                              void* d_out, int out_size, void* d_ws, size_t ws_size,
                              hipStream_t stream) {
    const int N = in_sizes[0];
    const int E = in_sizes[1] / 2;

    const int*   node_ids = (const int*)d_in[0];
    const int*   src      = (const int*)d_in[1];
    const int*   dst      = src + E;
    const float* eattr    = (const float*)d_in[2];
    const float* node_emb = (const float*)d_in[3];
    const float* l1_Wl = (const float*)d_in[4],  *l1_bl = (const float*)d_in[5];
    const float* l1_Wr = (const float*)d_in[6],  *l1_br = (const float*)d_in[7];
    const float* l1_We = (const float*)d_in[8],  *l1_att = (const float*)d_in[9];
    const float* l1_bias = (const float*)d_in[10];
    const float* l2_Wl = (const float*)d_in[11], *l2_bl = (const float*)d_in[12];
    const float* l2_Wr = (const float*)d_in[13], *l2_br = (const float*)d_in[14];
    const float* l2_We = (const float*)d_in[15], *l2_att = (const float*)d_in[16];
    const float* l2_bias = (const float*)d_in[17];
    const float* l3_Wl = (const float*)d_in[18], *l3_bl = (const float*)d_in[19];
    const float* l3_Wr = (const float*)d_in[20], *l3_br = (const float*)d_in[21];
    const float* l3_We = (const float*)d_in[22], *l3_att = (const float*)d_in[23];
    const float* l3_bias = (const float*)d_in[24];
    const float* mW1 = (const float*)d_in[25], *mb1 = (const float*)d_in[26];
    const float* mW2 = (const float*)d_in[27], *mb2 = (const float*)d_in[28];
    const float* mW3 = (const float*)d_in[29], *mb3 = (const float*)d_in[30];
    float* out = (float*)d_out;

    // ---- workspace layout (floats), 256B-aligned slices ----
    float* base = (float*)d_ws;
    size_t o = 0;
    auto alloc = [&](size_t n) { float* p = base + o; o += (n + 63) & ~(size_t)63; return p; };
    float* acc1  = alloc((size_t)N * 64);
    float* acc2  = alloc((size_t)N * 32);
    float* acc3  = alloc((size_t)N * 16);
    float* ssum1 = alloc((size_t)N * 4);
    float* ssum2 = alloc((size_t)N * 2);
    float* ssum3 = alloc((size_t)N);
    unsigned* mkey1 = (unsigned*)alloc((size_t)N * 4);
    unsigned* mkey2 = (unsigned*)alloc((size_t)N * 2);
    unsigned* mkey3 = (unsigned*)alloc((size_t)N);
    const size_t zero_end = o;           // everything above must start at 0
    float* xl = alloc((size_t)N * 64);
    float* xr = alloc((size_t)N * 64);
    float* x1 = alloc((size_t)N * 64);
    float* x2 = alloc((size_t)N * 32);
    float* x3 = alloc((size_t)N * 16);
    float* lg1 = alloc((size_t)E * 4);
    float* lg2 = alloc((size_t)E * 2);
    float* lg3 = alloc((size_t)E);
    (void)ws_size; (void)n_in; (void)out_size;

    const int gridE2 = (E + 127) / 128;   // all gat_edge configs use TILE_E = 128

    zero_kernel<<<1024, 256, 0, stream>>>(base, (long)zero_end);

    // ---- layer 1: in=32, H=4, C=16 (HC=64), concat ----
    node_transform<32, 64><<<(N + 3) / 4, 256, 0, stream>>>(
        node_emb, node_ids, l1_Wl, l1_bl, l1_Wr, l1_br, xl, xr, N);
    gat_edge<64, 8, 4><<<gridE2, 256, 0, stream>>>(
        eattr, xl, xr, l1_We, l1_att, src, dst, lg1, mkey1, E);
    softmax_ex<4><<<(E * 4 + 255) / 256, 256, 0, stream>>>(lg1, mkey1, ssum1, dst, E);
    aggregate<64><<<(int)(((long)E * 64 + 255) / 256), 256, 0, stream>>>(
        lg1, ssum1, xl, src, dst, acc1, E);
    finalize_k<<<(N * 64 + 255) / 256, 256, 0, stream>>>(acc1, l1_bias, x1, N * 64, 64, 1);

    // ---- layer 2: in=64, H=2, C=16 (HC=32), concat ----
    node_transform<64, 32><<<(N + 7) / 8, 256, 0, stream>>>(
        x1, nullptr, l2_Wl, l2_bl, l2_Wr, l2_br, xl, xr, N);
    gat_edge<32, 4, 4><<<gridE2, 256, 0, stream>>>(
        eattr, xl, xr, l2_We, l2_att, src, dst, lg2, mkey2, E);
    softmax_ex<2><<<(E * 2 + 255) / 256, 256, 0, stream>>>(lg2, mkey2, ssum2, dst, E);
    aggregate<32><<<(int)(((long)E * 32 + 255) / 256), 256, 0, stream>>>(
        lg2, ssum2, xl, src, dst, acc2, E);
    finalize_k<<<(N * 32 + 255) / 256, 256, 0, stream>>>(acc2, l2_bias, x2, N * 32, 32, 1);

    // ---- layer 3: in=32, H=1, C=16 (HC=16), mean (H=1 -> identity), no ELU ----
    node_transform<32, 16><<<(N + 15) / 16, 256, 0, stream>>>(
        x2, nullptr, l3_Wl, l3_bl, l3_Wr, l3_br, xl, xr, N);
    gat_edge<16, 4, 2><<<gridE2, 256, 0, stream>>>(
        eattr, xl, xr, l3_We, l3_att, src, dst, lg3, mkey3, E);
    softmax_ex<1><<<(E + 255) / 256, 256, 0, stream>>>(lg3, mkey3, ssum3, dst, E);
    aggregate<16><<<(int)(((long)E * 16 + 255) / 256), 256, 0, stream>>>(
        lg3, ssum3, xl, src, dst, acc3, E);
    finalize_k<<<(N * 16 + 255) / 256, 256, 0, stream>>>(acc3, l3_bias, x3, N * 16, 16, 0);

    // ---- edge MLP ----
    edge_mlp<<<(E + 255) / 256, 256, 0, stream>>>(
        x3, src, dst, mW1, mb1, mW2, mb2, mW3, mb3, out, E);
}